// Round 12
// baseline (507.748 us; speedup 1.0000x reference)
//
#include <hip/hip_runtime.h>
#include <hip/hip_bf16.h>
#include <stdint.h>

#define NN 8192
#define DD 128
#define CAP 160

typedef float f32x4 __attribute__((ext_vector_type(4)));
typedef unsigned int u32x4 __attribute__((ext_vector_type(4)));
typedef unsigned short u16x4 __attribute__((ext_vector_type(4)));
typedef __bf16 bf16x8 __attribute__((ext_vector_type(8)));
typedef __bf16 bf16x4 __attribute__((ext_vector_type(4)));

__device__ __forceinline__ f32x4 mfma16(bf16x8 a, bf16x8 b, f32x4 c) {
    return __builtin_amdgcn_mfma_f32_16x16x32_bf16(a, b, c, 0, 0, 0);
}

__device__ __forceinline__ bf16x8 pack8(f32x4 lo, f32x4 hi) {
    bf16x8 r;
    r[0] = (__bf16)lo[0]; r[1] = (__bf16)lo[1]; r[2] = (__bf16)lo[2]; r[3] = (__bf16)lo[3];
    r[4] = (__bf16)hi[0]; r[5] = (__bf16)hi[1]; r[6] = (__bf16)hi[2]; r[7] = (__bf16)hi[3];
    return r;
}

__device__ __forceinline__ float fast_sigmoid(float x) {
    return __builtin_amdgcn_rcpf(1.0f + __expf(-x));
}

// ---------------- kernel 1: W_D|W_C|W1|W2 -> bf16 ----------------
__global__ __launch_bounds__(256) void k_conv_w(
    const float* __restrict__ W_D, const float* __restrict__ W_C,
    const float* __restrict__ W1, const float* __restrict__ W2,
    __bf16* __restrict__ Wb)
{
    const int t = blockIdx.x * 256 + threadIdx.x;    // 0..16383
    const int m = t >> 12, i = t & 4095;
    const float* src = (m == 0) ? W_D : (m == 1) ? W_C : (m == 2) ? W1 : W2;
    const f32x4 v = *(const f32x4*)(src + i * 4);
    bf16x4 b;
    b[0] = (__bf16)v[0]; b[1] = (__bf16)v[1]; b[2] = (__bf16)v[2]; b[3] = (__bf16)v[3];
    *(bf16x4*)(Wb + m * 16384 + i * 4) = b;
}

// ---------------- kernel 2: E, XR (bf16 row-major, UNSCALED), YB (blocked), REA -------
// YB blocked layout: element (k, col) at (k>>5)*4096 + col*32 + (k&31).
__global__ __launch_bounds__(256) void k_prep2(
    const float* __restrict__ Z, const float* __restrict__ wV,
    const __bf16* __restrict__ Wb, const float* __restrict__ b1,
    const float* __restrict__ b2, const float* __restrict__ delta_logit,
    float* __restrict__ E, __bf16* __restrict__ XR, __bf16* __restrict__ YB,
    __bf16* __restrict__ REA)
{
    __shared__ __bf16 Hs[32][136];
    const int tid = threadIdx.x;
    const int w = tid >> 6, l = tid & 63;
    const int lr = l & 15, lg = l >> 4;
    const int wr = w & 1, wn = w >> 1;
    const int r0 = blockIdx.x * 32;

    // E = exp(Z @ w_V): 8 threads per row
    {
        const int erow = r0 + (tid >> 3);
        const int e0 = (tid & 7) * 16;
        const float* zp = Z + erow * DD + e0;
        float p = 0.f;
        #pragma unroll
        for (int q = 0; q < 4; ++q) {
            const f32x4 zv = *(const f32x4*)(zp + 4 * q);
            const f32x4 wv = *(const f32x4*)(wV + e0 + 4 * q);
            p += zv[0] * wv[0] + zv[1] * wv[1] + zv[2] * wv[2] + zv[3] * wv[3];
        }
        p += __shfl_xor(p, 4, 64);
        p += __shfl_xor(p, 2, 64);
        p += __shfl_xor(p, 1, 64);
        if ((tid & 7) == 0) E[erow] = __expf(p);
    }

    const int arow = r0 + 16 * wr + lr;
    const __bf16* WDb = Wb;
    const __bf16* WCb = Wb + 16384;
    const __bf16* W1b = Wb + 32768;
    const __bf16* W2b = Wb + 49152;

    const f32x4 zero4 = {0.f, 0.f, 0.f, 0.f};
    f32x4 aXD[4], aY[4], aH[4];
    #pragma unroll
    for (int i = 0; i < 4; ++i) { aXD[i] = zero4; aY[i] = zero4; aH[i] = zero4; }

    #pragma unroll
    for (int t = 0; t < 4; ++t) {
        const int k0 = 32 * t + 8 * lg;
        const bf16x8 af = pack8(*(const f32x4*)(Z + arow * DD + k0),
                                *(const f32x4*)(Z + arow * DD + k0 + 4));
        #pragma unroll
        for (int nf = 0; nf < 4; ++nf) {
            const int col = 64 * wn + 16 * nf + lr;
            aXD[nf] = mfma16(af, *(const bf16x8*)(WDb + col * DD + k0), aXD[nf]);
            aY[nf]  = mfma16(af, *(const bf16x8*)(WCb + col * DD + k0), aY[nf]);
            aH[nf]  = mfma16(af, *(const bf16x8*)(W1b + col * DD + k0), aH[nf]);
        }
    }

    const int orow = r0 + 16 * wr + 4 * lg;
    const int tile = orow >> 5;
    #pragma unroll
    for (int nf = 0; nf < 4; ++nf) {
        const int col = 64 * wn + 16 * nf + lr;
        bf16x4 yo;
        const float bb1 = b1[col];
        #pragma unroll
        for (int r = 0; r < 4; ++r) {
            XR[(orow + r) * DD + col] = (__bf16)aXD[nf][r];
            yo[r] = (__bf16)aY[nf][r];
            const float x = aH[nf][r] + bb1;
            const float e = __expf(2.0f * x);
            Hs[16 * wr + 4 * lg + r][col] = (__bf16)(1.0f - 2.0f * __builtin_amdgcn_rcpf(e + 1.0f));
        }
        *(bf16x4*)(YB + tile * 4096 + col * 32 + (orow & 31)) = yo;
    }
    __syncthreads();

    f32x4 aR[4];
    #pragma unroll
    for (int i = 0; i < 4; ++i) aR[i] = zero4;
    #pragma unroll
    for (int t = 0; t < 4; ++t) {
        const int k0 = 32 * t + 8 * lg;
        const bf16x8 hf = *(const bf16x8*)(&Hs[16 * wr + lr][k0]);
        #pragma unroll
        for (int nf = 0; nf < 4; ++nf) {
            const int col = 64 * wn + 16 * nf + lr;
            aR[nf] = mfma16(hf, *(const bf16x8*)(W2b + col * DD + k0), aR[nf]);
        }
    }
    const float delta = fast_sigmoid(delta_logit[0]);
    #pragma unroll
    for (int nf = 0; nf < 4; ++nf) {
        const int col = 64 * wn + 16 * nf + lr;
        const float bb2 = b2[col];
        #pragma unroll
        for (int r = 0; r < 4; ++r)
            REA[(orow + r) * DD + col] = (__bf16)(delta * (aR[nf][r] + bb2));
    }
}

// ---------------- kernel 3 (merged): A-scan blocks + con-GEMM blocks ----------------
// grid 2560: bid%5==0 -> con block (cid=bid/5, 512 total), else scan block (2048).
// Interleave guarantees each CU hosts a mix of memory-streaming (scan) and
// VALU/MFMA (con) blocks -> phases overlap (m114 co-scheduling).
__global__ __launch_bounds__(256) __attribute__((amdgpu_waves_per_eu(4)))
void k_merge(const float* __restrict__ A, const float* __restrict__ E,
             const __bf16* __restrict__ YB, uint32_t* __restrict__ mask,
             float* __restrict__ dsq, float* __restrict__ CON,
             float* __restrict__ den)
{
    __shared__ float red[2][64][40];     // 20KB reduce buffers (con blocks only)
    const int bid = blockIdx.x;
    const int tid = threadIdx.x;
    const int w = tid >> 6, l = tid & 63;

    if (bid % 5 != 0) {
        // ---- scan path: pure per-lane bitmask stream ----
        const int sidx = bid - bid / 5 - 1;          // 0..2047
        const int row = sidx * 4 + w;
        const float* rp = A + (size_t)row * NN + l * 4;
        uint32_t* mrow = mask + (size_t)row * 256;
        uint32_t dcnt = 0;
        #pragma unroll
        for (int g = 0; g < 4; ++g) {
            uint32_t mw = 0;
            #pragma unroll
            for (int t = 0; t < 8; ++t) {
                const f32x4 v = *(const f32x4*)(rp + (g * 8 + t) * 256);
                const uint32_t nb = (v[0] != 0.f ? 1u : 0u) | (v[1] != 0.f ? 2u : 0u)
                                  | (v[2] != 0.f ? 4u : 0u) | (v[3] != 0.f ? 8u : 0u);
                mw |= nb << (t * 4);
            }
            mrow[g * 64 + l] = mw;
            dcnt += __popc(mw);
        }
        #pragma unroll
        for (int off = 32; off > 0; off >>= 1) dcnt += __shfl_xor((int)dcnt, off, 64);
        if (l == 0) dsq[row] = (dcnt > 0) ? 1.0f / sqrtf((float)dcnt) : 0.0f;
        return;
    }

    // ---- con path: 16 rows x 128 cols, 4 waves split K (2048 each) ----
    const int cid = bid / 5;
    const int r0 = cid * 16;
    const int lr = l & 15, lg = l >> 4;
    const int kstart = w * 2048;
    const float* ep = E + kstart + 8 * lg;
    const __bf16* yp = YB + (kstart >> 5) * 4096 + lr * 32 + 8 * lg;
    const float u0 = E[r0 + lr];

    const f32x4 zero4 = {0.f, 0.f, 0.f, 0.f};
    f32x4 aC[8];
    #pragma unroll
    for (int i = 0; i < 8; ++i) aC[i] = zero4;
    float dn = 0.f;

    f32x4 eAa, eBa, eAb, eBb;
    bf16x8 bya[8], byb[8];
    intptr_t adv = 32;

#define LOADT(S) do {                                                         \
        eA##S = *(const f32x4*)(ep); eB##S = *(const f32x4*)(ep + 4);         \
        _Pragma("unroll")                                                     \
        for (int c = 0; c < 8; ++c) by##S[c] = *(const bf16x8*)(yp + c * 512);\
        ep += adv; yp += adv * 128;                                           \
    } while (0)

#define COMPT(S) do {                                                         \
        bf16x8 gf;                                                            \
        _Pragma("unroll")                                                     \
        for (int j = 0; j < 4; ++j) {                                         \
            const float s0 = u0 * __builtin_amdgcn_rcpf(u0 + eA##S[j]);       \
            const float s1 = u0 * __builtin_amdgcn_rcpf(u0 + eB##S[j]);       \
            const float g0 = __expf(s0), g1 = __expf(s1);                     \
            gf[j] = (__bf16)g0; gf[4 + j] = (__bf16)g1;                       \
            dn += g0 + g1;                                                    \
        }                                                                     \
        _Pragma("unroll")                                                     \
        for (int c = 0; c < 8; ++c) aC[c] = mfma16(gf, by##S[c], aC[c]);      \
    } while (0)

    LOADT(a);                              // tile 0
    for (int it = 0; it < 32; ++it) {      // 64 tiles total
        if (it == 31) adv = 0;
        LOADT(b); COMPT(a);
        LOADT(a); COMPT(b);
    }
#undef LOADT
#undef COMPT

    // tree reduce 4 -> 2 -> 1 into wave 0
    __syncthreads();
    if (w >= 2) {
        float* s = &red[w - 2][l][0];
        #pragma unroll
        for (int c = 0; c < 8; ++c) *(f32x4*)(s + 4 * c) = aC[c];
        s[32] = dn;
    }
    __syncthreads();
    if (w < 2) {
        const float* s = &red[w][l][0];
        #pragma unroll
        for (int c = 0; c < 8; ++c) aC[c] += *(const f32x4*)(s + 4 * c);
        dn += s[32];
    }
    __syncthreads();
    if (w == 1) {
        float* s = &red[0][l][0];
        #pragma unroll
        for (int c = 0; c < 8; ++c) *(f32x4*)(s + 4 * c) = aC[c];
        s[32] = dn;
    }
    __syncthreads();
    if (w == 0) {
        const float* s = &red[0][l][0];
        #pragma unroll
        for (int c = 0; c < 8; ++c) aC[c] += *(const f32x4*)(s + 4 * c);
        dn += s[32];
        dn += __shfl_xor(dn, 16, 64);
        dn += __shfl_xor(dn, 32, 64);
        #pragma unroll
        for (int c = 0; c < 8; ++c) {
            #pragma unroll
            for (int r = 0; r < 4; ++r)
                CON[(size_t)(r0 + 4 * lg + r) * DD + 16 * c + lr] = aC[c][r];
        }
        if (l < 16) den[r0 + l] = dn;
    }
}

// ---------------- kernel 4: mask decode + dif gather + epilogue ----------------
// grid 512 (16 rows each), 256 threads. High occupancy (5KB LDS, low VGPR).
__global__ __launch_bounds__(256) void k_fin(
    const uint32_t* __restrict__ mask, const __bf16* __restrict__ XR,
    const __bf16* __restrict__ REA, const float* __restrict__ dsq,
    const float* __restrict__ CON, const float* __restrict__ den,
    const float* __restrict__ omega_logit, float* __restrict__ out)
{
    __shared__ uint16_t ents16[16][CAP];
    __shared__ uint32_t cnt32[16];
    const int tid = threadIdx.x;
    const int r0 = blockIdx.x * 16;
    const int row = tid >> 4, g16 = tid & 15;

    if (tid < 16) cnt32[tid] = 0;
    __syncthreads();
    {
        const uint32_t* mrow = mask + (size_t)(r0 + row) * 256 + g16 * 16;
        #pragma unroll
        for (int q = 0; q < 4; ++q) {
            const u32x4 mv = *(const u32x4*)(mrow + q * 4);
            #pragma unroll
            for (int s = 0; s < 4; ++s) {
                uint32_t m = mv[s];
                const int widx = g16 * 16 + q * 4 + s;
                const int cbase = (widx >> 6) * 8;
                const int coff = (widx & 63) * 4;
                while (m) {
                    const int b = __ffs(m) - 1; m &= m - 1;
                    const int col = (cbase + (b >> 2)) * 256 + coff + (b & 3);
                    const uint32_t slot = atomicAdd(&cnt32[row], 1u);
                    if (slot < CAP) ents16[row][slot] = (uint16_t)col;
                }
            }
        }
    }
    __syncthreads();

    const int col0 = 8 * g16;
    const int rg = r0 + row;
    float acc[8];
    #pragma unroll
    for (int i = 0; i < 8; ++i) acc[i] = 0.0f;

    const uint32_t n = min(cnt32[row], (uint32_t)CAP);
    uint32_t e = 0;
    for (; e + 4 <= n; e += 4) {
        const u16x4 p = *(const u16x4*)(&ents16[row][e]);
        const float d0 = dsq[p[0]], d1 = dsq[p[1]], d2 = dsq[p[2]], d3 = dsq[p[3]];
        const bf16x8 x0 = *(const bf16x8*)(XR + (size_t)p[0] * DD + col0);
        const bf16x8 x1 = *(const bf16x8*)(XR + (size_t)p[1] * DD + col0);
        const bf16x8 x2 = *(const bf16x8*)(XR + (size_t)p[2] * DD + col0);
        const bf16x8 x3 = *(const bf16x8*)(XR + (size_t)p[3] * DD + col0);
        #pragma unroll
        for (int i = 0; i < 8; ++i)
            acc[i] += d0 * (float)x0[i] + d1 * (float)x1[i]
                    + d2 * (float)x2[i] + d3 * (float)x3[i];
    }
    for (; e < n; ++e) {
        const uint16_t pc = ents16[row][e];
        const float dv = dsq[pc];
        const bf16x8 xv = *(const bf16x8*)(XR + (size_t)pc * DD + col0);
        #pragma unroll
        for (int i = 0; i < 8; ++i) acc[i] += dv * (float)xv[i];
    }

    const float omega = fast_sigmoid(omega_logit[0]);
    const float om1 = 1.0f - omega;
    const float dsqi = dsq[rg];
    const float dinv = __builtin_amdgcn_rcpf(den[rg]);
    const bf16x8 rea8 = *(const bf16x8*)(REA + (size_t)rg * DD + col0);
    const float* cp = CON + (size_t)rg * DD + col0;
    f32x4 o0, o1;
    #pragma unroll
    for (int i = 0; i < 8; ++i) {
        const float dv = fmaxf(dsqi * acc[i], 0.0f);
        const float cv = cp[i] * dinv;
        const float v = (float)rea8[i] + omega * dv + om1 * cv;
        if (i < 4) o0[i] = v; else o1[i - 4] = v;
    }
    *(f32x4*)(out + (size_t)rg * DD + col0) = o0;
    *(f32x4*)(out + (size_t)rg * DD + col0 + 4) = o1;
}

extern "C" void kernel_launch(void* const* d_in, const int* in_sizes, int n_in,
                              void* d_out, int out_size, void* d_ws, size_t ws_size,
                              hipStream_t stream) {
    (void)in_sizes; (void)n_in; (void)out_size; (void)ws_size;
    const float* Z   = (const float*)d_in[0];
    const float* A   = (const float*)d_in[1];
    const float* W_D = (const float*)d_in[2];
    const float* W_C = (const float*)d_in[3];
    const float* wV  = (const float*)d_in[4];
    const float* W1  = (const float*)d_in[5];
    const float* b1  = (const float*)d_in[6];
    const float* W2  = (const float*)d_in[7];
    const float* b2  = (const float*)d_in[8];
    const float* omega_logit = (const float*)d_in[9];
    const float* delta_logit = (const float*)d_in[10];
    float* out = (float*)d_out;

    // ws layout (bytes):
    // E 0 | Wb 32K | XR 160K | YB +2M | REA +2M | dsq +2M | mask | CON | den  (~18.2MB)
    char* wsb = (char*)d_ws;
    float*    E    = (float*)wsb;
    __bf16*   Wb   = (__bf16*)(wsb + 32768);
    __bf16*   XR   = (__bf16*)(wsb + 163840);
    __bf16*   YB   = (__bf16*)(wsb + 2260992);
    __bf16*   REA  = (__bf16*)(wsb + 4358144);
    float*    dsq  = (float*)(wsb + 6455296);
    uint32_t* mask = (uint32_t*)(wsb + 6488064);
    float*    CON  = (float*)(wsb + 14876672);
    float*    den  = (float*)(wsb + 19070976);

    k_conv_w<<<dim3(64), dim3(256), 0, stream>>>(W_D, W_C, W1, W2, Wb);
    k_prep2<<<dim3(256), dim3(256), 0, stream>>>(Z, wV, Wb, b1, b2, delta_logit,
                                                 E, XR, YB, REA);
    k_merge<<<dim3(2560), dim3(256), 0, stream>>>(A, E, YB, mask, dsq, CON, den);
    k_fin<<<dim3(512), dim3(256), 0, stream>>>(mask, XR, REA, dsq, CON, den,
                                               omega_logit, out);
}